// Round 23
// baseline (784.746 us; speedup 1.0000x reference)
//
#include <hip/hip_runtime.h>
#include <hip/hip_bf16.h>
#include <math.h>

#define N_NODES  50000
#define N_EDGES  800000
#define E_TOT    850000   /* edges + self loops */
#define N_GRAPHS 64
#define N_LOCS   50
#define SCAN_B   ((N_NODES + 255) / 256)   /* 196 scan blocks */
#define TSTRIDE  128                       /* bf16 T row stride: 256B, 4 lines */

typedef __hip_bfloat16 bf16;

// ---------------- static scratch ----------------
__device__ int      g_dt[20];                    // float inputs: 0=bf16, 1=f32, 2=f64
__device__ int      g_iw;                        // int inputs: 1 = int64, 0 = int32
__device__ int      g_deg[N_NODES];
__device__ int      g_cursor[N_NODES];
__device__ int      g_rowptr[N_NODES + 1];
__device__ int      g_bsum[SCAN_B];
__device__ int      g_csrc[E_TOT];               // CSR: src node per slot
__device__ float    g_Wp[129 * 132];             // padded f32 weight for current layer
__device__ __align__(256) unsigned short g_Tb[(size_t)N_NODES * TSTRIDE]; // T cols 0..127 (bf16)
__device__ float    g_Te[N_NODES];               // T col 128 (f32)
__device__ float    g_H[(size_t)N_NODES * 129];  // layer output (f32)
__device__ float    g_es[N_NODES * 3];
__device__ float    g_ed[N_NODES * 3];
__device__ unsigned g_gmk[9];                    // per-layer global es max keys (3 heads x 3 layers)
__device__ float    g_gsum[N_GRAPHS * 128];
__device__ float    g_gcnt[N_GRAPHS];

// ---------------- helpers ----------------
__device__ __forceinline__ float b2f(bf16 x){ return __bfloat162float(x); }
__device__ __forceinline__ float lrelu(float x){ return x > 0.f ? x : 0.2f * x; }
__device__ __forceinline__ int   clampi(int v, int lo, int hi){ return v < lo ? lo : (v > hi ? hi : v); }
__device__ __forceinline__ float finz(float v){
    unsigned u = __float_as_uint(v);
    return ((u & 0x7F800000u) == 0x7F800000u) ? 0.f : v;   // NaN/inf -> 0
}
__device__ __forceinline__ unsigned short f2bu(float x){
    union { bf16 b; unsigned short u; } cv; cv.b = __float2bfloat16(x); return cv.u;
}
__device__ __forceinline__ float bu2f(unsigned short u){ return __uint_as_float(((unsigned)u) << 16); }
// order-preserving float<->unsigned key (0 reserved as "empty" sentinel)
__device__ __forceinline__ unsigned fkey(float f){
    unsigned u = __float_as_uint(f);
    return (u & 0x80000000u) ? ~u : (u | 0x80000000u);
}
__device__ __forceinline__ float kinv(unsigned k){
    return __uint_as_float((k & 0x80000000u) ? (k ^ 0x80000000u) : ~k);
}
// dtype-dispatching sanitized float input load: 0=bf16, 1=f32, 2=f64
__device__ __forceinline__ float ldin(const void* p, int m, size_t i){
    float v = (m == 2) ? (float)((const double*)p)[i]
            : (m == 1) ? ((const float*)p)[i]
            :            b2f(((const bf16*)p)[i]);
    return finz(v);
}
__device__ __forceinline__ int ldi(const void* p, int wide, size_t i){
    return wide ? (int)((const long long*)p)[i] : ((const int*)p)[i];
}
__device__ __forceinline__ float expc(float a){ return __expf(fminf(fmaxf(a, -80.f), 0.f)); }
// edge -> (src,dst) including self-loops
__device__ __forceinline__ void edge_sd(const void* ei, int wide, int e, int& src, int& dst){
    if (e < N_EDGES){
        src = clampi(ldi(ei, wide, e), 0, N_NODES - 1);
        dst = clampi(ldi(ei, wide, (size_t)N_EDGES + e), 0, N_NODES - 1);
    } else {
        src = dst = e - N_EDGES;
    }
}

// ---------------- dtype detection (1 wave) ----------------
__global__ void k_detect(const void* x, const void* loc, const void* W0,
                         const void* as0, const void* ad0, const void* W1,
                         const void* as1, const void* ad1, const void* W2,
                         const void* as2, const void* ad2, const void* Wl1,
                         const void* Wl2, const void* ei){
    const void* ps[13] = {x, loc, W0, as0, ad0, W1, as1, ad1, W2, as2, ad2, Wl1, Wl2};
    const int  sl[13]  = {0,  1,   4,  5,   6,   8,  9,   10,  12, 13,  14,  16,  18};
    int lane = threadIdx.x;   // 64 lanes
    for (int t = 0; t < 13; t++){
        float vf = ((const float*)ps[t])[lane];
        unsigned uf = __float_as_uint(vf);
        bool hit64 = ((uf & 0x7F800000u) == 0x7F800000u) || fabsf(vf) > 1e4f;
        int n64 = __popcll(__ballot(hit64));

        float vb = b2f(((const bf16*)ps[t])[lane]);
        unsigned ub = __float_as_uint(vb);
        bool hit32 = ((ub & 0x7F800000u) == 0x7F800000u) || fabsf(vb) > 1e4f;
        int n32 = __popcll(__ballot(hit32));

        if (lane == 0) g_dt[sl[t]] = (n64 >= 2) ? 2 : ((n32 >= 2) ? 1 : 0);
    }
    int w0 = ((const int*)ei)[lane];
    unsigned long long zm = __ballot((lane & 1) && (w0 == 0));
    if (lane == 0){
        g_iw = (__popcll(zm) >= 16) ? 1 : 0;
        g_dt[2] = g_dt[3] = 0;
        g_dt[7] = g_dt[11] = g_dt[15] = 0;
        g_dt[17] = g_dt[19] = 0;
    }
}

// ---------------- zero init ----------------
__global__ void k_zero_global(){
    int i = blockIdx.x * blockDim.x + threadIdx.x;
    if (i < N_NODES) g_deg[i] = 0;
    if (i < N_GRAPHS * 128) g_gsum[i] = 0.f;
    if (i < 9) g_gmk[i] = 0u;
}

// ---------------- CSR build (once per call) ----------------
__global__ void k_deg(const void* __restrict__ ei){
    int wide = g_iw;
    int e = blockIdx.x * blockDim.x + threadIdx.x;
    if (e >= E_TOT) return;
    int src, dst; edge_sd(ei, wide, e, src, dst);
    atomicAdd(&g_deg[dst], 1);
}

__global__ void k_scan1(){
    __shared__ int s[256];
    int i = blockIdx.x * 256 + threadIdx.x;
    int v = (i < N_NODES) ? g_deg[i] : 0;
    s[threadIdx.x] = v;
    __syncthreads();
    for (int off = 1; off < 256; off <<= 1){
        int add = (threadIdx.x >= off) ? s[threadIdx.x - off] : 0;
        __syncthreads();
        s[threadIdx.x] += add;
        __syncthreads();
    }
    if (threadIdx.x == 255) g_bsum[blockIdx.x] = s[255];
    if (i < N_NODES) g_rowptr[i] = s[threadIdx.x] - v;
}

__global__ void k_scan2(){
    int lane = threadIdx.x;
    int carry = 0;
    for (int base = 0; base < SCAN_B; base += 64){
        int i = base + lane;
        int v = (i < SCAN_B) ? g_bsum[i] : 0;
        int s = v;
        #pragma unroll
        for (int off = 1; off < 64; off <<= 1){
            int t = __shfl_up(s, off);
            if (lane >= off) s += t;
        }
        if (i < SCAN_B) g_bsum[i] = carry + s - v;
        carry += __shfl(s, 63);
    }
    if (lane == 0) g_rowptr[N_NODES] = carry;
}

__global__ void k_scan3(){
    int i = blockIdx.x * 256 + threadIdx.x;
    if (i < N_NODES){
        int r = g_rowptr[i] + g_bsum[blockIdx.x];
        g_rowptr[i] = r;
        g_cursor[i] = r;
    }
}

__global__ void k_fillcsr(const void* __restrict__ ei){
    int wide = g_iw;
    int e = blockIdx.x * blockDim.x + threadIdx.x;
    if (e >= E_TOT) return;
    int src, dst; edge_sd(ei, wide, e, src, dst);
    int pos = atomicAdd(&g_cursor[dst], 1);
    if (pos >= 0 && pos < E_TOT) g_csrc[pos] = src;
}

// ---------------- GEMMs (write bf16 T, col 128 -> g_Te f32) -----------------
__global__ void k_gemm0(const void* __restrict__ x, const void* __restrict__ W){
    int dtx = g_dt[0], dtw = g_dt[4];
    int idx = blockIdx.x * blockDim.x + threadIdx.x;
    if (idx >= N_NODES * 129) return;
    int n = idx / 129, c = idx - n * 129;
    float acc = 0.f;
    #pragma unroll
    for (int k = 0; k < 6; k++)
        acc += ldin(x, dtx, (size_t)n * 6 + k) * ldin(W, dtw, k * 129 + c);
    if (c < 128) g_Tb[(size_t)n * TSTRIDE + c] = f2bu(finz(acc));
    else         g_Te[n] = finz(acc);
}

// pad/convert W [K][CO] -> g_Wp [K][132] (f32, sanitized) — once per layer
template<int K, int CO>
__global__ void k_prepW(const void* __restrict__ W, int slot){
    int m = g_dt[slot];
    int idx = blockIdx.x * blockDim.x + threadIdx.x;
    if (idx >= K * 132) return;
    int k = idx / 132, c = idx - k * 132;
    g_Wp[idx] = (c < CO) ? ldin(W, m, (size_t)k * CO + c) : 0.f;
}

// vectorized GEMM, 4 rows/thread: block = 32 rows x 32 col-groups, bf16 out
template<int K, int CO>
__global__ __launch_bounds__(256)
void k_gemmf(){
    int tid = threadIdx.x;
    int rg = tid >> 5;                  // 0..7
    int g  = tid & 31;
    int n0 = blockIdx.x * 32 + rg * 4;  // 4 consecutive rows per thread
    const float4* wp = (const float4*)g_Wp;   // [K][33] float4s
    float4 acc[4];
    float accE[4];
    const float* ar[4];
    #pragma unroll
    for (int r = 0; r < 4; r++){
        acc[r] = make_float4(0.f, 0.f, 0.f, 0.f);
        accE[r] = 0.f;
        int n = n0 + r;
        ar[r] = g_H + (size_t)(n < N_NODES ? n : N_NODES - 1) * K;
    }
    #pragma unroll 2
    for (int k = 0; k < K; k++){
        float4 w = wp[k * 33 + g];
        float we = (CO > 128 && g == 0) ? g_Wp[k * 132 + 128] : 0.f;
        #pragma unroll
        for (int r = 0; r < 4; r++){
            float a = ar[r][k];
            acc[r].x += a * w.x; acc[r].y += a * w.y;
            acc[r].z += a * w.z; acc[r].w += a * w.w;
            if (CO > 128 && g == 0) accE[r] += a * we;
        }
    }
    #pragma unroll
    for (int r = 0; r < 4; r++){
        int n = n0 + r;
        if (n >= N_NODES) break;
        unsigned* tw = (unsigned*)(g_Tb + (size_t)n * TSTRIDE);
        tw[g * 2]     = ((unsigned)f2bu(acc[r].y) << 16) | f2bu(acc[r].x);
        tw[g * 2 + 1] = ((unsigned)f2bu(acc[r].w) << 16) | f2bu(acc[r].z);
        if (CO > 128 && g == 0) g_Te[n] = finz(accE[r]);
    }
}

// ---------------- per-node attention coefficients (bf16 T reads) ------------
template<int H, int O, int C>
__global__ void k_esed(const void* __restrict__ as, const void* __restrict__ ad,
                       int slot_as, int slot_ad){
    int dta = g_dt[slot_as], dtd = g_dt[slot_ad];
    int idx = blockIdx.x * blockDim.x + threadIdx.x;
    if (idx >= N_NODES * H) return;
    int n = idx / H, h = idx - n * H;
    float a = 0.f, b = 0.f;
    #pragma unroll 4
    for (int o = 0; o < O; o++){
        int col = h * O + o;
        float v = (col < 128) ? bu2f(g_Tb[(size_t)n * TSTRIDE + col]) : finz(g_Te[n]);
        a += v * ldin(as, dta, h * O + o);
        b += v * ldin(ad, dtd, h * O + o);
    }
    g_es[idx] = finz(a); g_ed[idx] = finz(b);
}

// ---------------- per-layer global es max (upper bound for softmax shift) ---
template<int H>
__global__ void k_gmax(int base){
    __shared__ unsigned sm[3];
    int tid = threadIdx.x;
    if (tid < H) sm[tid] = 0u;
    __syncthreads();
    int i = blockIdx.x * 256 + tid;
    if (i < N_NODES){
        #pragma unroll
        for (int h = 0; h < H; h++)
            atomicMax(&sm[h], fkey(finz(g_es[i * H + h])));
    }
    __syncthreads();
    if (tid < H) atomicMax(&g_gmk[base + tid], sm[tid]);
}

// ------- FUSED softmax+gather, single edge sweep ----------------------------
// Softmax shift uses the per-node upper bound B[h] = lrelu(gmax_es[h]+ed[h])
// (>= exact max since lrelu monotone) — exp args stay <= 0, and the shift
// cancels exactly in a/z. No max pass needed.
// Edges in chunks of CH=64/H: phase A lane l computes exp-weight for edge l/H,
// head l%H (one exp per lane per chunk); phase B serial gather via __shfl.
template<int H, int O, int C, bool LEAKY>
__global__ __launch_bounds__(256)
void k_fgat(const void* __restrict__ bias, int slot_b, int base){
    const int CH = 64 / H;               // 21 for H=3, 64 for H=1
    int dtb = g_dt[slot_b];
    int wv = threadIdx.x >> 6, lane = threadIdx.x & 63;
    int n = blockIdx.x * 4 + wv;
    if (n >= N_NODES) return;
    int r0 = clampi(g_rowptr[n], 0, E_TOT);
    int r1 = clampi(g_rowptr[n + 1], r0, E_TOT);

    float edv[H], mx[H];
    #pragma unroll
    for (int h = 0; h < H; h++){
        edv[h] = finz(g_ed[n * H + h]);
        mx[h] = lrelu(finz(kinv(g_gmk[base + h])) + edv[h]);   // upper bound
    }

    const int c0 = 2 * lane, c1 = 2 * lane + 1;
    const int h0 = c0 / O, h1 = c1 / O;
    const int jmine = lane / H;          // my edge slot within chunk
    const int hmine = lane - jmine * H;  // my head
    const float edm = edv[hmine], mxm = mx[hmine];
    float a0 = 0.f, a1 = 0.f, a2 = 0.f;
    float zA = 0.f, zB = 0.f, zL = 0.f;
    for (int bse = r0; bse < r1; bse += CH){
        int m = r1 - bse; if (m > CH) m = CH;
        // phase A: cooperative weight computation (1 exp per lane)
        float w = 0.f; int sA = 0;
        if (jmine < m){
            sA = clampi(g_csrc[bse + jmine], 0, N_NODES - 1);
            w = expc(lrelu(finz(g_es[sA * H + hmine]) + edm) - mxm);
        }
        // phase B: serial gather over chunk edges
        for (int t = 0; t < m; t++){
            int s    = __shfl(sA, t * H);
            float wA = __shfl(w, t * H + h0);
            float wB = __shfl(w, t * H + h1);
            float wL = __shfl(w, t * H + (H - 1));
            const unsigned* tr = (const unsigned*)(g_Tb + (size_t)s * TSTRIDE);
            unsigned pv = tr[lane];
            a0 += wA * __uint_as_float(pv << 16);
            a1 += wB * __uint_as_float(pv & 0xFFFF0000u);
            zA += wA; zB += wB;
            if (C > 128 && lane == 0){
                a2 += wL * finz(g_Te[s]);
                zL += wL;
            }
        }
    }
    float o0 = finz(a0 / (zA + 1e-16f)) + ldin(bias, dtb, c0);
    float o1 = finz(a1 / (zB + 1e-16f)) + ldin(bias, dtb, c1);
    if (LEAKY){ o0 = lrelu(o0); o1 = lrelu(o1); }
    g_H[(size_t)n * C + c0] = finz(o0);
    g_H[(size_t)n * C + c1] = finz(o1);
    if (C > 128 && lane == 0){
        float o2 = finz(a2 / (zL + 1e-16f)) + ldin(bias, dtb, 128);
        if (LEAKY) o2 = lrelu(o2);
        g_H[(size_t)n * C + 128] = finz(o2);
    }
}

// ---------------- pooling (batch is sorted by construction) ----------------
__global__ void k_poolA(const void* __restrict__ batch){
    int wide = g_iw;
    int c = threadIdx.x;              // 128 channels
    int n0 = blockIdx.x * 128;
    int bprev = -1; float acc = 0.f;
    for (int j = 0; j < 128; j++){
        int n = n0 + j;
        if (n >= N_NODES) break;
        int b = clampi(ldi(batch, wide, n), 0, N_GRAPHS - 1);
        if (b != bprev){
            if (bprev >= 0) atomicAdd(&g_gsum[bprev * 128 + c], acc);
            acc = 0.f; bprev = b;
        }
        acc += finz(g_H[(size_t)n * 128 + c]);
    }
    if (bprev >= 0) atomicAdd(&g_gsum[bprev * 128 + c], acc);
}

// per-graph node count via binary search on sorted batch (no atomics)
__global__ void k_cnt(const void* __restrict__ batch){
    int wide = g_iw;
    int b = threadIdx.x;              // 64 threads
    if (b >= N_GRAPHS) return;
    int lo = 0, hi = N_NODES;
    while (lo < hi){ int mid = (lo + hi) >> 1; if (ldi(batch, wide, mid) <  b) lo = mid + 1; else hi = mid; }
    int start = lo;
    lo = 0; hi = N_NODES;
    while (lo < hi){ int mid = (lo + hi) >> 1; if (ldi(batch, wide, mid) <= b) lo = mid + 1; else hi = mid; }
    g_gcnt[b] = (float)(lo - start);
}

// output is float32 (established r13/r14)
__global__ void k_fin(float* __restrict__ out){
    int idx = blockIdx.x * blockDim.x + threadIdx.x;
    if (idx >= N_GRAPHS * 128) return;
    int b = idx >> 7, c = idx & 127;
    out[b * 256 + c] = finz(finz(g_gsum[idx]) / fmaxf(g_gcnt[b], 1.f));
}

// ---------------- location-encoder MLP: fast two-stage (LDS) ----------------
__global__ void k_loc(const void* __restrict__ loc, const void* __restrict__ Wl1,
                      const void* __restrict__ bl1, const void* __restrict__ Wl2,
                      const void* __restrict__ bl2, float* __restrict__ out){
    int dtl = g_dt[1], dtw1 = g_dt[16], dtb1 = g_dt[17], dtw2 = g_dt[18], dtb2 = g_dt[19];
    int b = blockIdx.x, t = threadIdx.x;   // 64 blocks x 256 threads
    __shared__ float hs[256];
    float w0 = ldin(Wl1, dtw1, t);
    float w1 = ldin(Wl1, dtw1, 256 + t);
    float bb = ldin(bl1, dtb1, t);
    float s = 0.f;
    #pragma unroll 5
    for (int l = 0; l < N_LOCS; l++){
        float x0 = ldin(loc, dtl, ((size_t)b * N_LOCS + l) * 2);
        float x1 = ldin(loc, dtl, ((size_t)b * N_LOCS + l) * 2 + 1);
        s += tanhf(x0 * w0 + x1 * w1 + bb);
    }
    hs[t] = s;
    __syncthreads();
    if (t < 128){
        float acc = 0.f;
        #pragma unroll 8
        for (int j = 0; j < 256; j++) acc += hs[j] * ldin(Wl2, dtw2, (size_t)j * 128 + t);
        out[(size_t)b * 256 + 128 + t] = finz(acc * (1.f / (float)N_LOCS) + ldin(bl2, dtb2, t));
    }
}

// ---------------- per-layer driver ----------------
template<int H, int O, int C, bool LEAKY>
static void gat_layer(const void* as, const void* ad, const void* bias,
                      int s_as, int s_ad, int s_b, int gbase, hipStream_t stream){
    const int NH  = (N_NODES * H + 255) / 256;
    const int GB  = (N_NODES + 3) / 4;          // one wave per node
    k_esed<H, O, C><<<NH, 256, 0, stream>>>(as, ad, s_as, s_ad);
    k_gmax<H><<<SCAN_B, 256, 0, stream>>>(gbase);
    k_fgat<H, O, C, LEAKY><<<GB, 256, 0, stream>>>(bias, s_b, gbase);
}

// ---------------- launch ----------------
extern "C" void kernel_launch(void* const* d_in, const int* in_sizes, int n_in,
                              void* d_out, int out_size, void* d_ws, size_t ws_size,
                              hipStream_t stream){
    static const int want[20] = {300000, 6400, 1600000, 50000,
                                 774, 129, 129, 129,
                                 16641, 129, 129, 129,
                                 16512, 128, 128, 128,
                                 512, 256, 32768, 128};
    const void* P[20];
    bool assigned[20];
    for (int s = 0; s < 20; s++){ P[s] = nullptr; assigned[s] = false; }
    bool ok = (n_in == 20);
    if (ok){
        for (int i = 0; i < 20; i++){
            int sz = in_sizes[i], hit = -1;
            for (int s = 0; s < 20; s++)
                if (!assigned[s] && want[s] == sz){ hit = s; break; }
            if (hit < 0){ ok = false; break; }
            P[hit] = d_in[i]; assigned[hit] = true;
        }
        for (int s = 0; s < 20 && ok; s++) if (!assigned[s]) ok = false;
    }
    if (!ok) for (int s = 0; s < 20 && s < n_in; s++) P[s] = d_in[s];

    const void* x    = P[0];
    const void* loc  = P[1];
    const void* ei   = P[2];
    const void* batch= P[3];
    const void* W0   = P[4];
    const void* as0  = P[5];
    const void* ad0  = P[6];
    const void* b0   = P[7];
    const void* W1   = P[8];
    const void* as1  = P[9];
    const void* ad1  = P[10];
    const void* b1   = P[11];
    const void* W2   = P[12];
    const void* as2  = P[13];
    const void* ad2  = P[14];
    const void* b2   = P[15];
    const void* Wl1  = P[16];
    const void* bl1  = P[17];
    const void* Wl2  = P[18];
    const void* bl2  = P[19];
    float* out = (float*)d_out;
    (void)d_ws; (void)ws_size; (void)out_size;

    const int EB = (E_TOT + 255) / 256;
    const int GEMM_B = (N_NODES + 31) / 32;
    k_detect<<<1, 64, 0, stream>>>(x, loc, W0, as0, ad0, W1, as1, ad1, W2, as2, ad2, Wl1, Wl2, ei);
    k_zero_global<<<(N_NODES + 255) / 256, 256, 0, stream>>>();

    // CSR build (graph shared by all 3 layers) — parallel 3-stage scan
    k_deg    <<<EB, 256, 0, stream>>>(ei);
    k_scan1  <<<SCAN_B, 256, 0, stream>>>();
    k_scan2  <<<1, 64, 0, stream>>>();
    k_scan3  <<<SCAN_B, 256, 0, stream>>>();
    k_fillcsr<<<EB, 256, 0, stream>>>(ei);

    // layer 0
    k_gemm0<<<(N_NODES * 129 + 255) / 256, 256, 0, stream>>>(x, W0);
    gat_layer<3, 43, 129, true>(as0, ad0, b0, 5, 6, 7, 0, stream);

    // layer 1
    k_prepW<129, 129><<<(129 * 132 + 255) / 256, 256, 0, stream>>>(W1, 8);
    k_gemmf<129, 129><<<GEMM_B, 256, 0, stream>>>();
    gat_layer<3, 43, 129, true>(as1, ad1, b1, 9, 10, 11, 3, stream);

    // layer 2
    k_prepW<129, 128><<<(129 * 132 + 255) / 256, 256, 0, stream>>>(W2, 12);
    k_gemmf<129, 128><<<GEMM_B, 256, 0, stream>>>();
    gat_layer<1, 128, 128, false>(as2, ad2, b2, 13, 14, 15, 6, stream);

    // pooling + output (f32 stores)
    k_poolA<<<(N_NODES + 127) / 128, 128, 0, stream>>>(batch);
    k_cnt  <<<1, 64, 0, stream>>>(batch);
    k_fin  <<<(N_GRAPHS * 128 + 255) / 256, 256, 0, stream>>>(out);
    k_loc  <<<N_GRAPHS, 256, 0, stream>>>(loc, Wl1, bl1, Wl2, bl2, out);
}

// Round 25
// 651.900 us; speedup vs baseline: 1.2038x; 1.2038x over previous
//
#include <hip/hip_runtime.h>
#include <hip/hip_bf16.h>
#include <math.h>

#define N_NODES  50000
#define N_EDGES  800000
#define E_TOT    850000   /* edges + self loops */
#define N_GRAPHS 64
#define N_LOCS   50
#define SCAN_B   ((N_NODES + 255) / 256)   /* 196 scan blocks */
#define TSTRIDE  128                       /* bf16 T row stride: 256B, 4 lines */

typedef __hip_bfloat16 bf16;

// ---------------- static scratch ----------------
__device__ int      g_deg[N_NODES];
__device__ int      g_cursor[N_NODES];
__device__ int      g_rowptr[N_NODES + 1];
__device__ int      g_bsum[SCAN_B];
__device__ int      g_csrc[E_TOT];               // CSR: src node per slot
__device__ float    g_Wp0[6 * 132];              // padded f32 weights per layer
__device__ float    g_Wp1[129 * 132];
__device__ float    g_Wp2[129 * 132];
__device__ __align__(256) unsigned short g_Tb[(size_t)N_NODES * TSTRIDE]; // T cols 0..127 (bf16)
__device__ float    g_Te[N_NODES];               // T col 128 (f32)
__device__ float    g_H[(size_t)N_NODES * 129];  // layer output (f32)
__device__ float    g_es[N_NODES * 3];
__device__ float    g_ed[N_NODES * 3];
__device__ unsigned g_gmk[9];                    // per-layer global es max keys
__device__ float    g_gsum[N_GRAPHS * 128];
__device__ float    g_gcnt[N_GRAPHS];

// ---------------- helpers (dtypes settled: floats f32, ints int32) ----------
__device__ __forceinline__ float lrelu(float x){ return x > 0.f ? x : 0.2f * x; }
__device__ __forceinline__ int   clampi(int v, int lo, int hi){ return v < lo ? lo : (v > hi ? hi : v); }
__device__ __forceinline__ float finz(float v){
    unsigned u = __float_as_uint(v);
    return ((u & 0x7F800000u) == 0x7F800000u) ? 0.f : v;   // NaN/inf -> 0
}
__device__ __forceinline__ unsigned short f2bu(float x){
    union { bf16 b; unsigned short u; } cv; cv.b = __float2bfloat16(x); return cv.u;
}
__device__ __forceinline__ float bu2f(unsigned short u){ return __uint_as_float(((unsigned)u) << 16); }
__device__ __forceinline__ unsigned fkey(float f){
    unsigned u = __float_as_uint(f);
    return (u & 0x80000000u) ? ~u : (u | 0x80000000u);
}
__device__ __forceinline__ float kinv(unsigned k){
    return __uint_as_float((k & 0x80000000u) ? (k ^ 0x80000000u) : ~k);
}
__device__ __forceinline__ float expc(float a){ return __expf(fminf(fmaxf(a, -80.f), 0.f)); }
__device__ __forceinline__ void edge_sd(const int* ei, int e, int& src, int& dst){
    if (e < N_EDGES){
        src = clampi(ei[e], 0, N_NODES - 1);
        dst = clampi(ei[N_EDGES + e], 0, N_NODES - 1);
    } else {
        src = dst = e - N_EDGES;
    }
}

// ---------------- fused preprocessing: zero + pad all weights ---------------
// linear task space: [deg 50000][gsum 8192][gmk 9][Wp0 792][Wp1 17028][Wp2 17028]
#define PRE_TOT (N_NODES + N_GRAPHS*128 + 9 + 6*132 + 129*132 + 129*132)
__global__ void k_pre(const float* __restrict__ W0, const float* __restrict__ W1,
                      const float* __restrict__ W2){
    int i = blockIdx.x * blockDim.x + threadIdx.x;
    if (i < N_NODES){ g_deg[i] = 0; return; }
    i -= N_NODES;
    if (i < N_GRAPHS * 128){ g_gsum[i] = 0.f; return; }
    i -= N_GRAPHS * 128;
    if (i < 9){ g_gmk[i] = 0u; return; }
    i -= 9;
    if (i < 6 * 132){
        int k = i / 132, c = i - k * 132;
        g_Wp0[i] = (c < 129) ? finz(W0[k * 129 + c]) : 0.f;
        return;
    }
    i -= 6 * 132;
    if (i < 129 * 132){
        int k = i / 132, c = i - k * 132;
        g_Wp1[i] = (c < 129) ? finz(W1[k * 129 + c]) : 0.f;
        return;
    }
    i -= 129 * 132;
    if (i < 129 * 132){
        int k = i / 132, c = i - k * 132;
        g_Wp2[i] = (c < 128) ? finz(W2[k * 128 + c]) : 0.f;
    }
}

// ---------------- CSR build ----------------
__global__ void k_deg(const int* __restrict__ ei){
    int e = blockIdx.x * blockDim.x + threadIdx.x;
    if (e >= E_TOT) return;
    int src, dst; edge_sd(ei, e, src, dst);
    atomicAdd(&g_deg[dst], 1);
}

__global__ void k_scan1(){
    __shared__ int s[256];
    int i = blockIdx.x * 256 + threadIdx.x;
    int v = (i < N_NODES) ? g_deg[i] : 0;
    s[threadIdx.x] = v;
    __syncthreads();
    for (int off = 1; off < 256; off <<= 1){
        int add = (threadIdx.x >= off) ? s[threadIdx.x - off] : 0;
        __syncthreads();
        s[threadIdx.x] += add;
        __syncthreads();
    }
    if (threadIdx.x == 255) g_bsum[blockIdx.x] = s[255];
    if (i < N_NODES) g_rowptr[i] = s[threadIdx.x] - v;
}

__global__ void k_scan2(){
    int lane = threadIdx.x;
    int carry = 0;
    for (int base = 0; base < SCAN_B; base += 64){
        int i = base + lane;
        int v = (i < SCAN_B) ? g_bsum[i] : 0;
        int s = v;
        #pragma unroll
        for (int off = 1; off < 64; off <<= 1){
            int t = __shfl_up(s, off);
            if (lane >= off) s += t;
        }
        if (i < SCAN_B) g_bsum[i] = carry + s - v;
        carry += __shfl(s, 63);
    }
    if (lane == 0) g_rowptr[N_NODES] = carry;
}

__global__ void k_scan3(){
    int i = blockIdx.x * 256 + threadIdx.x;
    if (i < N_NODES){
        int r = g_rowptr[i] + g_bsum[blockIdx.x];
        g_rowptr[i] = r;
        g_cursor[i] = r;
    }
}

__global__ void k_fillcsr(const int* __restrict__ ei){
    int e = blockIdx.x * blockDim.x + threadIdx.x;
    if (e >= E_TOT) return;
    int src, dst; edge_sd(ei, e, src, dst);
    int pos = atomicAdd(&g_cursor[dst], 1);
    if (pos >= 0 && pos < E_TOT) g_csrc[pos] = src;
}

// ---------------- GEMM: 4 rows/thread, float4 W, bf16 out -------------------
// LAYER selects A and Wp IN DEVICE CODE (device globals must not be passed
// as kernel args from host — r24 crash).
template<int K, int CO, int LAYER>
__global__ __launch_bounds__(256)
void k_gemmf(const float* __restrict__ X){
    const float* A  = (LAYER == 0) ? X : g_H;
    const float* Wp = (LAYER == 0) ? g_Wp0 : (LAYER == 1 ? g_Wp1 : g_Wp2);
    int tid = threadIdx.x;
    int rg = tid >> 5;
    int g  = tid & 31;
    int n0 = blockIdx.x * 32 + rg * 4;
    const float4* wp = (const float4*)Wp;     // [K][33] float4s
    float4 acc[4];
    float accE[4];
    const float* ar[4];
    #pragma unroll
    for (int r = 0; r < 4; r++){
        acc[r] = make_float4(0.f, 0.f, 0.f, 0.f);
        accE[r] = 0.f;
        int n = n0 + r;
        ar[r] = A + (size_t)(n < N_NODES ? n : N_NODES - 1) * K;
    }
    #pragma unroll 2
    for (int k = 0; k < K; k++){
        float4 w = wp[k * 33 + g];
        float we = (CO > 128 && g == 0) ? Wp[k * 132 + 128] : 0.f;
        #pragma unroll
        for (int r = 0; r < 4; r++){
            float a = ar[r][k];
            acc[r].x += a * w.x; acc[r].y += a * w.y;
            acc[r].z += a * w.z; acc[r].w += a * w.w;
            if (CO > 128 && g == 0) accE[r] += a * we;
        }
    }
    #pragma unroll
    for (int r = 0; r < 4; r++){
        int n = n0 + r;
        if (n >= N_NODES) break;
        unsigned* tw = (unsigned*)(g_Tb + (size_t)n * TSTRIDE);
        tw[g * 2]     = ((unsigned)f2bu(finz(acc[r].x)) ) | ((unsigned)f2bu(finz(acc[r].y)) << 16);
        tw[g * 2 + 1] = ((unsigned)f2bu(finz(acc[r].z)) ) | ((unsigned)f2bu(finz(acc[r].w)) << 16);
        if (CO > 128 && g == 0) g_Te[n] = finz(accE[r]);
    }
}

// ---------------- attention coefficients + fused global-max epilogue --------
template<int H, int O, int C>
__global__ void k_esed(const float* __restrict__ as, const float* __restrict__ ad,
                       int base){
    __shared__ unsigned sm[3];
    int tid = threadIdx.x;
    if (tid < H) sm[tid] = 0u;
    __syncthreads();
    int idx = blockIdx.x * blockDim.x + tid;
    if (idx < N_NODES * H){
        int n = idx / H, h = idx - n * H;
        float a = 0.f, b = 0.f;
        #pragma unroll 4
        for (int o = 0; o < O; o++){
            int col = h * O + o;
            float v = (col < 128) ? bu2f(g_Tb[(size_t)n * TSTRIDE + col]) : finz(g_Te[n]);
            a += v * finz(as[h * O + o]);
            b += v * finz(ad[h * O + o]);
        }
        a = finz(a); b = finz(b);
        g_es[idx] = a; g_ed[idx] = b;
        atomicMax(&sm[h], fkey(a));
    }
    __syncthreads();
    if (tid < H) atomicMax(&g_gmk[base + tid], sm[tid]);
}

// ------- FUSED softmax+gather, single edge sweep, 2-edge unrolled -----------
template<int H, int O, int C, bool LEAKY>
__global__ __launch_bounds__(256)
void k_fgat(const float* __restrict__ bias, int base){
    const int CH = 64 / H;               // 21 for H=3, 64 for H=1
    int wv = threadIdx.x >> 6, lane = threadIdx.x & 63;
    int n = blockIdx.x * 4 + wv;
    if (n >= N_NODES) return;
    int r0 = clampi(g_rowptr[n], 0, E_TOT);
    int r1 = clampi(g_rowptr[n + 1], r0, E_TOT);

    float edv[H], mx[H];
    #pragma unroll
    for (int h = 0; h < H; h++){
        edv[h] = finz(g_ed[n * H + h]);
        mx[h] = lrelu(finz(kinv(g_gmk[base + h])) + edv[h]);   // upper bound
    }

    const int c0 = 2 * lane, c1 = 2 * lane + 1;
    const int h0 = c0 / O, h1 = c1 / O;
    const int jmine = lane / H;
    const int hmine = lane - jmine * H;
    const float edm = edv[hmine], mxm = mx[hmine];
    float a0 = 0.f, a1 = 0.f, a2 = 0.f;
    float zA = 0.f, zB = 0.f, zL = 0.f;
    for (int bse = r0; bse < r1; bse += CH){
        int m = r1 - bse; if (m > CH) m = CH;
        // phase A: cooperative weight computation (1 exp per lane)
        float w = 0.f; int sA = 0;
        if (jmine < m){
            sA = clampi(g_csrc[bse + jmine], 0, N_NODES - 1);
            w = expc(lrelu(finz(g_es[sA * H + hmine]) + edm) - mxm);
        }
        // phase B: gather, 2 edges per iteration (2 row loads in flight)
        int t = 0;
        for (; t + 1 < m; t += 2){
            int s0 = __shfl(sA, t * H);
            int s1 = __shfl(sA, (t + 1) * H);
            float wA0 = __shfl(w, t * H + h0);
            float wB0 = __shfl(w, t * H + h1);
            float wA1 = __shfl(w, (t + 1) * H + h0);
            float wB1 = __shfl(w, (t + 1) * H + h1);
            float wL0 = __shfl(w, t * H + (H - 1));
            float wL1 = __shfl(w, (t + 1) * H + (H - 1));
            unsigned pv0 = ((const unsigned*)(g_Tb + (size_t)s0 * TSTRIDE))[lane];
            unsigned pv1 = ((const unsigned*)(g_Tb + (size_t)s1 * TSTRIDE))[lane];
            a0 += wA0 * __uint_as_float(pv0 << 16);
            a1 += wB0 * __uint_as_float(pv0 & 0xFFFF0000u);
            zA += wA0; zB += wB0;
            a0 += wA1 * __uint_as_float(pv1 << 16);
            a1 += wB1 * __uint_as_float(pv1 & 0xFFFF0000u);
            zA += wA1; zB += wB1;
            if (C > 128 && lane == 0){
                a2 += wL0 * finz(g_Te[s0]); zL += wL0;
                a2 += wL1 * finz(g_Te[s1]); zL += wL1;
            }
        }
        if (t < m){
            int s0 = __shfl(sA, t * H);
            float wA0 = __shfl(w, t * H + h0);
            float wB0 = __shfl(w, t * H + h1);
            float wL0 = __shfl(w, t * H + (H - 1));
            unsigned pv0 = ((const unsigned*)(g_Tb + (size_t)s0 * TSTRIDE))[lane];
            a0 += wA0 * __uint_as_float(pv0 << 16);
            a1 += wB0 * __uint_as_float(pv0 & 0xFFFF0000u);
            zA += wA0; zB += wB0;
            if (C > 128 && lane == 0){
                a2 += wL0 * finz(g_Te[s0]); zL += wL0;
            }
        }
    }
    float o0 = finz(a0 / (zA + 1e-16f)) + finz(bias[c0]);
    float o1 = finz(a1 / (zB + 1e-16f)) + finz(bias[c1]);
    if (LEAKY){ o0 = lrelu(o0); o1 = lrelu(o1); }
    g_H[(size_t)n * C + c0] = finz(o0);
    g_H[(size_t)n * C + c1] = finz(o1);
    if (C > 128 && lane == 0){
        float o2 = finz(a2 / (zL + 1e-16f)) + finz(bias[128]);
        if (LEAKY) o2 = lrelu(o2);
        g_H[(size_t)n * C + 128] = finz(o2);
    }
}

// ---------------- pooling (batch sorted by construction) --------------------
__global__ void k_poolA(const int* __restrict__ batch){
    int c = threadIdx.x;              // 128 channels
    int n0 = blockIdx.x * 128;
    int bprev = -1; float acc = 0.f;
    for (int j = 0; j < 128; j++){
        int n = n0 + j;
        if (n >= N_NODES) break;
        int b = clampi(batch[n], 0, N_GRAPHS - 1);
        if (b != bprev){
            if (bprev >= 0) atomicAdd(&g_gsum[bprev * 128 + c], acc);
            acc = 0.f; bprev = b;
        }
        acc += finz(g_H[(size_t)n * 128 + c]);
    }
    if (bprev >= 0) atomicAdd(&g_gsum[bprev * 128 + c], acc);
}

// output is float32 (established r13/r14)
__global__ void k_fin(float* __restrict__ out){
    int idx = blockIdx.x * blockDim.x + threadIdx.x;
    if (idx >= N_GRAPHS * 128) return;
    int b = idx >> 7, c = idx & 127;
    out[b * 256 + c] = finz(finz(g_gsum[idx]) / fmaxf(g_gcnt[b], 1.f));
}

// ---------------- location MLP (+ per-graph count in block 64) --------------
__global__ void k_loc(const float* __restrict__ loc, const float* __restrict__ Wl1,
                      const float* __restrict__ bl1, const float* __restrict__ Wl2,
                      const float* __restrict__ bl2, float* __restrict__ out,
                      const int* __restrict__ batch){
    int b = blockIdx.x, t = threadIdx.x;
    if (b == N_GRAPHS){   // block 64: per-graph node counts via binary search
        if (t < N_GRAPHS){
            int lo = 0, hi = N_NODES;
            while (lo < hi){ int mid = (lo + hi) >> 1; if (batch[mid] <  t) lo = mid + 1; else hi = mid; }
            int start = lo;
            lo = 0; hi = N_NODES;
            while (lo < hi){ int mid = (lo + hi) >> 1; if (batch[mid] <= t) lo = mid + 1; else hi = mid; }
            g_gcnt[t] = (float)(lo - start);
        }
        return;
    }
    __shared__ float hs[256];
    float w0 = finz(Wl1[t]);
    float w1 = finz(Wl1[256 + t]);
    float bb = finz(bl1[t]);
    float s = 0.f;
    #pragma unroll 5
    for (int l = 0; l < N_LOCS; l++){
        float x0 = finz(loc[((size_t)b * N_LOCS + l) * 2]);
        float x1 = finz(loc[((size_t)b * N_LOCS + l) * 2 + 1]);
        s += tanhf(x0 * w0 + x1 * w1 + bb);
    }
    hs[t] = s;
    __syncthreads();
    if (t < 128){
        float acc = 0.f;
        #pragma unroll 8
        for (int j = 0; j < 256; j++) acc += hs[j] * finz(Wl2[(size_t)j * 128 + t]);
        out[(size_t)b * 256 + 128 + t] = finz(acc * (1.f / (float)N_LOCS) + finz(bl2[t]));
    }
}

// ---------------- launch ----------------
extern "C" void kernel_launch(void* const* d_in, const int* in_sizes, int n_in,
                              void* d_out, int out_size, void* d_ws, size_t ws_size,
                              hipStream_t stream){
    static const int want[20] = {300000, 6400, 1600000, 50000,
                                 774, 129, 129, 129,
                                 16641, 129, 129, 129,
                                 16512, 128, 128, 128,
                                 512, 256, 32768, 128};
    const void* P[20];
    bool assigned[20];
    for (int s = 0; s < 20; s++){ P[s] = nullptr; assigned[s] = false; }
    bool ok = (n_in == 20);
    if (ok){
        for (int i = 0; i < 20; i++){
            int sz = in_sizes[i], hit = -1;
            for (int s = 0; s < 20; s++)
                if (!assigned[s] && want[s] == sz){ hit = s; break; }
            if (hit < 0){ ok = false; break; }
            P[hit] = d_in[i]; assigned[hit] = true;
        }
        for (int s = 0; s < 20 && ok; s++) if (!assigned[s]) ok = false;
    }
    if (!ok) for (int s = 0; s < 20 && s < n_in; s++) P[s] = d_in[s];

    const float* x    = (const float*)P[0];
    const float* loc  = (const float*)P[1];
    const int*   ei   = (const int*)  P[2];
    const int*   batch= (const int*)  P[3];
    const float* W0   = (const float*)P[4];
    const float* as0  = (const float*)P[5];
    const float* ad0  = (const float*)P[6];
    const float* b0   = (const float*)P[7];
    const float* W1   = (const float*)P[8];
    const float* as1  = (const float*)P[9];
    const float* ad1  = (const float*)P[10];
    const float* b1   = (const float*)P[11];
    const float* W2   = (const float*)P[12];
    const float* as2  = (const float*)P[13];
    const float* ad2  = (const float*)P[14];
    const float* b2   = (const float*)P[15];
    const float* Wl1  = (const float*)P[16];
    const float* bl1  = (const float*)P[17];
    const float* Wl2  = (const float*)P[18];
    const float* bl2  = (const float*)P[19];
    float* out = (float*)d_out;
    (void)d_ws; (void)ws_size; (void)out_size;

    const int EB = (E_TOT + 255) / 256;
    const int GEMM_B = (N_NODES + 31) / 32;
    const int GB = (N_NODES + 3) / 4;

    k_pre    <<<(PRE_TOT + 255) / 256, 256, 0, stream>>>(W0, W1, W2);
    k_deg    <<<EB, 256, 0, stream>>>(ei);
    k_scan1  <<<SCAN_B, 256, 0, stream>>>();
    k_scan2  <<<1, 64, 0, stream>>>();
    k_scan3  <<<SCAN_B, 256, 0, stream>>>();
    k_fillcsr<<<EB, 256, 0, stream>>>(ei);

    // layer 0
    k_gemmf<6, 129, 0><<<GEMM_B, 256, 0, stream>>>(x);
    k_esed<3, 43, 129><<<(N_NODES * 3 + 255) / 256, 256, 0, stream>>>(as0, ad0, 0);
    k_fgat<3, 43, 129, true><<<GB, 256, 0, stream>>>(b0, 0);

    // layer 1
    k_gemmf<129, 129, 1><<<GEMM_B, 256, 0, stream>>>(x);
    k_esed<3, 43, 129><<<(N_NODES * 3 + 255) / 256, 256, 0, stream>>>(as1, ad1, 3);
    k_fgat<3, 43, 129, true><<<GB, 256, 0, stream>>>(b1, 3);

    // layer 2
    k_gemmf<129, 128, 2><<<GEMM_B, 256, 0, stream>>>(x);
    k_esed<1, 128, 128><<<(N_NODES + 255) / 256, 256, 0, stream>>>(as2, ad2, 6);
    k_fgat<1, 128, 128, false><<<GB, 256, 0, stream>>>(b2, 6);

    // pooling + output
    k_poolA<<<(N_NODES + 127) / 128, 128, 0, stream>>>(batch);
    k_loc  <<<N_GRAPHS + 1, 256, 0, stream>>>(loc, Wl1, bl1, Wl2, bl2, out, batch);
    k_fin  <<<(N_GRAPHS * 128 + 255) / 256, 256, 0, stream>>>(out);
}

// Round 26
// 609.515 us; speedup vs baseline: 1.2875x; 1.0695x over previous
//
#include <hip/hip_runtime.h>
#include <hip/hip_bf16.h>
#include <math.h>

#define N_NODES  50000
#define N_EDGES  800000
#define E_TOT    850000   /* edges + self loops */
#define N_GRAPHS 64
#define N_LOCS   50
#define SCAN_B   ((N_NODES + 255) / 256)   /* 196 scan blocks */
#define TSTRIDE  128                       /* bf16 T row stride: 256B, 4 lines */
#define HSTRIDE  132                       /* f32 H row stride: 528B, 16B-aligned */

typedef __hip_bfloat16 bf16;

// ---------------- static scratch ----------------
__device__ int      g_deg[N_NODES];
__device__ int      g_cursor[N_NODES];
__device__ int      g_rowptr[N_NODES + 1];
__device__ int      g_bsum[SCAN_B];
__device__ int      g_csrc[E_TOT];               // CSR: src node per slot
__device__ float    g_Wp0[6 * 132];              // padded f32 weights per layer
__device__ float    g_Wp1[132 * 132];            // K zero-padded to 132 rows
__device__ float    g_Wp2[132 * 132];
__device__ __align__(256) unsigned short g_Tb[(size_t)N_NODES * TSTRIDE]; // T cols 0..127 (bf16)
__device__ float    g_Te[N_NODES];               // T col 128 (f32)
__device__ __align__(16) float g_H[(size_t)N_NODES * HSTRIDE]; // layer output (f32, pad cols zero)
__device__ float    g_es[N_NODES * 3];
__device__ float    g_ed[N_NODES * 3];
__device__ unsigned g_gmk[9];                    // per-layer global es max keys
__device__ float    g_gsum[N_GRAPHS * 128];
__device__ float    g_gcnt[N_GRAPHS];

// ---------------- helpers (dtypes settled: floats f32, ints int32) ----------
__device__ __forceinline__ float lrelu(float x){ return x > 0.f ? x : 0.2f * x; }
__device__ __forceinline__ int   clampi(int v, int lo, int hi){ return v < lo ? lo : (v > hi ? hi : v); }
__device__ __forceinline__ float finz(float v){
    unsigned u = __float_as_uint(v);
    return ((u & 0x7F800000u) == 0x7F800000u) ? 0.f : v;   // NaN/inf -> 0
}
__device__ __forceinline__ unsigned short f2bu(float x){
    union { bf16 b; unsigned short u; } cv; cv.b = __float2bfloat16(x); return cv.u;
}
__device__ __forceinline__ float bu2f(unsigned short u){ return __uint_as_float(((unsigned)u) << 16); }
__device__ __forceinline__ unsigned fkey(float f){
    unsigned u = __float_as_uint(f);
    return (u & 0x80000000u) ? ~u : (u | 0x80000000u);
}
__device__ __forceinline__ float kinv(unsigned k){
    return __uint_as_float((k & 0x80000000u) ? (k ^ 0x80000000u) : ~k);
}
__device__ __forceinline__ float expc(float a){ return __expf(fminf(fmaxf(a, -80.f), 0.f)); }
__device__ __forceinline__ void edge_sd(const int* ei, int e, int& src, int& dst){
    if (e < N_EDGES){
        src = clampi(ei[e], 0, N_NODES - 1);
        dst = clampi(ei[N_EDGES + e], 0, N_NODES - 1);
    } else {
        src = dst = e - N_EDGES;
    }
}

// ---------------- fused preprocessing: zero + pad all weights ---------------
// [deg 50000][gsum 8192][gmk 9][Wp0 792][Wp1 17424][Wp2 17424]
#define PRE_TOT (N_NODES + N_GRAPHS*128 + 9 + 6*132 + 132*132 + 132*132)
__global__ void k_pre(const float* __restrict__ W0, const float* __restrict__ W1,
                      const float* __restrict__ W2){
    int i = blockIdx.x * blockDim.x + threadIdx.x;
    if (i < N_NODES){ g_deg[i] = 0; return; }
    i -= N_NODES;
    if (i < N_GRAPHS * 128){ g_gsum[i] = 0.f; return; }
    i -= N_GRAPHS * 128;
    if (i < 9){ g_gmk[i] = 0u; return; }
    i -= 9;
    if (i < 6 * 132){
        int k = i / 132, c = i - k * 132;
        g_Wp0[i] = (c < 129) ? finz(W0[k * 129 + c]) : 0.f;
        return;
    }
    i -= 6 * 132;
    if (i < 132 * 132){
        int k = i / 132, c = i - k * 132;
        g_Wp1[i] = (k < 129 && c < 129) ? finz(W1[k * 129 + c]) : 0.f;
        return;
    }
    i -= 132 * 132;
    if (i < 132 * 132){
        int k = i / 132, c = i - k * 132;
        g_Wp2[i] = (k < 129 && c < 128) ? finz(W2[k * 128 + c]) : 0.f;
    }
}

// ---------------- CSR build ----------------
__global__ void k_deg(const int* __restrict__ ei){
    int e = blockIdx.x * blockDim.x + threadIdx.x;
    if (e >= E_TOT) return;
    int src, dst; edge_sd(ei, e, src, dst);
    atomicAdd(&g_deg[dst], 1);
}

__global__ void k_scan1(){
    __shared__ int s[256];
    int i = blockIdx.x * 256 + threadIdx.x;
    int v = (i < N_NODES) ? g_deg[i] : 0;
    s[threadIdx.x] = v;
    __syncthreads();
    for (int off = 1; off < 256; off <<= 1){
        int add = (threadIdx.x >= off) ? s[threadIdx.x - off] : 0;
        __syncthreads();
        s[threadIdx.x] += add;
        __syncthreads();
    }
    if (threadIdx.x == 255) g_bsum[blockIdx.x] = s[255];
    if (i < N_NODES) g_rowptr[i] = s[threadIdx.x] - v;
}

__global__ void k_scan2(){
    int lane = threadIdx.x;
    int carry = 0;
    for (int base = 0; base < SCAN_B; base += 64){
        int i = base + lane;
        int v = (i < SCAN_B) ? g_bsum[i] : 0;
        int s = v;
        #pragma unroll
        for (int off = 1; off < 64; off <<= 1){
            int t = __shfl_up(s, off);
            if (lane >= off) s += t;
        }
        if (i < SCAN_B) g_bsum[i] = carry + s - v;
        carry += __shfl(s, 63);
    }
    if (lane == 0) g_rowptr[N_NODES] = carry;
}

__global__ void k_scan3(){
    int i = blockIdx.x * 256 + threadIdx.x;
    if (i < N_NODES){
        int r = g_rowptr[i] + g_bsum[blockIdx.x];
        g_rowptr[i] = r;
        g_cursor[i] = r;
    }
}

__global__ void k_fillcsr(const int* __restrict__ ei){
    int e = blockIdx.x * blockDim.x + threadIdx.x;
    if (e >= E_TOT) return;
    int src, dst; edge_sd(ei, e, src, dst);
    int pos = atomicAdd(&g_cursor[dst], 1);
    if (pos >= 0 && pos < E_TOT) g_csrc[pos] = src;
}

// ---------------- GEMM: 4 rows/thread, float4 A and W, bf16 out -------------
// LAYER selects A/Wp in device code. Layers 1,2: A = g_H (stride 132,
// 16B-aligned), k-loop padded to 132 with zero W rows (extra terms == 0,
// real-term accumulation order unchanged).
template<int LAYER, int CO>
__global__ __launch_bounds__(256)
void k_gemmf(const float* __restrict__ X){
    const float* Wp = (LAYER == 0) ? g_Wp0 : (LAYER == 1 ? g_Wp1 : g_Wp2);
    int tid = threadIdx.x;
    int rg = tid >> 5;
    int g  = tid & 31;
    int n0 = blockIdx.x * 32 + rg * 4;
    const float4* wp = (const float4*)Wp;     // [rows][33] float4s
    float4 acc[4];
    float accE[4];
    #pragma unroll
    for (int r = 0; r < 4; r++){ acc[r] = make_float4(0.f,0.f,0.f,0.f); accE[r] = 0.f; }

    if (LAYER == 0){
        const float* ar[4];
        #pragma unroll
        for (int r = 0; r < 4; r++){
            int n = n0 + r;
            ar[r] = X + (size_t)(n < N_NODES ? n : N_NODES - 1) * 6;
        }
        #pragma unroll
        for (int k = 0; k < 6; k++){
            float4 w = wp[k * 33 + g];
            float we = (g == 0) ? Wp[k * 132 + 128] : 0.f;
            #pragma unroll
            for (int r = 0; r < 4; r++){
                float a = ar[r][k];
                acc[r].x += a * w.x; acc[r].y += a * w.y;
                acc[r].z += a * w.z; acc[r].w += a * w.w;
                if (g == 0) accE[r] += a * we;
            }
        }
    } else {
        const float4* ar[4];
        #pragma unroll
        for (int r = 0; r < 4; r++){
            int n = n0 + r;
            ar[r] = (const float4*)(g_H + (size_t)(n < N_NODES ? n : N_NODES - 1) * HSTRIDE);
        }
        for (int kk = 0; kk < 33; kk++){
            float4 a4[4];
            #pragma unroll
            for (int r = 0; r < 4; r++) a4[r] = ar[r][kk];
            #pragma unroll
            for (int j = 0; j < 4; j++){
                int k = kk * 4 + j;
                float4 w = wp[k * 33 + g];
                float we = (CO > 128 && g == 0) ? Wp[k * 132 + 128] : 0.f;
                #pragma unroll
                for (int r = 0; r < 4; r++){
                    float a = (j == 0) ? a4[r].x : (j == 1) ? a4[r].y : (j == 2) ? a4[r].z : a4[r].w;
                    acc[r].x += a * w.x; acc[r].y += a * w.y;
                    acc[r].z += a * w.z; acc[r].w += a * w.w;
                    if (CO > 128 && g == 0) accE[r] += a * we;
                }
            }
        }
    }

    #pragma unroll
    for (int r = 0; r < 4; r++){
        int n = n0 + r;
        if (n >= N_NODES) break;
        unsigned* tw = (unsigned*)(g_Tb + (size_t)n * TSTRIDE);
        tw[g * 2]     = ((unsigned)f2bu(finz(acc[r].x)) ) | ((unsigned)f2bu(finz(acc[r].y)) << 16);
        tw[g * 2 + 1] = ((unsigned)f2bu(finz(acc[r].z)) ) | ((unsigned)f2bu(finz(acc[r].w)) << 16);
        if (CO > 128 && g == 0) g_Te[n] = finz(accE[r]);
    }
}

// ---------------- attention coefficients + fused global-max epilogue --------
template<int H, int O, int C>
__global__ void k_esed(const float* __restrict__ as, const float* __restrict__ ad,
                       int base){
    __shared__ unsigned sm[3];
    int tid = threadIdx.x;
    if (tid < H) sm[tid] = 0u;
    __syncthreads();
    int idx = blockIdx.x * blockDim.x + tid;
    if (idx < N_NODES * H){
        int n = idx / H, h = idx - n * H;
        float a = 0.f, b = 0.f;
        #pragma unroll 4
        for (int o = 0; o < O; o++){
            int col = h * O + o;
            float v = (col < 128) ? bu2f(g_Tb[(size_t)n * TSTRIDE + col]) : finz(g_Te[n]);
            a += v * finz(as[h * O + o]);
            b += v * finz(ad[h * O + o]);
        }
        a = finz(a); b = finz(b);
        g_es[idx] = a; g_ed[idx] = b;
        atomicMax(&sm[h], fkey(a));
    }
    __syncthreads();
    if (tid < H) atomicMax(&g_gmk[base + tid], sm[tid]);
}

// ------- FUSED softmax+gather, single edge sweep, 2-edge unrolled -----------
template<int H, int O, int C, bool LEAKY>
__global__ __launch_bounds__(256)
void k_fgat(const float* __restrict__ bias, int base){
    const int CH = 64 / H;               // 21 for H=3, 64 for H=1
    int wv = threadIdx.x >> 6, lane = threadIdx.x & 63;
    int n = blockIdx.x * 4 + wv;
    if (n >= N_NODES) return;
    int r0 = clampi(g_rowptr[n], 0, E_TOT);
    int r1 = clampi(g_rowptr[n + 1], r0, E_TOT);

    float edv[H], mx[H];
    #pragma unroll
    for (int h = 0; h < H; h++){
        edv[h] = finz(g_ed[n * H + h]);
        mx[h] = lrelu(finz(kinv(g_gmk[base + h])) + edv[h]);   // upper bound
    }

    const int c0 = 2 * lane, c1 = 2 * lane + 1;
    const int h0 = c0 / O, h1 = c1 / O;
    const int jmine = lane / H;
    const int hmine = lane - jmine * H;
    const float edm = edv[hmine], mxm = mx[hmine];
    float a0 = 0.f, a1 = 0.f, a2 = 0.f;
    float zA = 0.f, zB = 0.f, zL = 0.f;
    for (int bse = r0; bse < r1; bse += CH){
        int m = r1 - bse; if (m > CH) m = CH;
        // phase A: cooperative weight computation (1 exp per lane)
        float w = 0.f; int sA = 0;
        if (jmine < m){
            sA = clampi(g_csrc[bse + jmine], 0, N_NODES - 1);
            w = expc(lrelu(finz(g_es[sA * H + hmine]) + edm) - mxm);
        }
        // phase B: gather, 2 edges per iteration (2 row loads in flight)
        int t = 0;
        for (; t + 1 < m; t += 2){
            int s0 = __shfl(sA, t * H);
            int s1 = __shfl(sA, (t + 1) * H);
            float wA0 = __shfl(w, t * H + h0);
            float wB0 = __shfl(w, t * H + h1);
            float wA1 = __shfl(w, (t + 1) * H + h0);
            float wB1 = __shfl(w, (t + 1) * H + h1);
            float wL0 = __shfl(w, t * H + (H - 1));
            float wL1 = __shfl(w, (t + 1) * H + (H - 1));
            unsigned pv0 = ((const unsigned*)(g_Tb + (size_t)s0 * TSTRIDE))[lane];
            unsigned pv1 = ((const unsigned*)(g_Tb + (size_t)s1 * TSTRIDE))[lane];
            a0 += wA0 * __uint_as_float(pv0 << 16);
            a1 += wB0 * __uint_as_float(pv0 & 0xFFFF0000u);
            zA += wA0; zB += wB0;
            a0 += wA1 * __uint_as_float(pv1 << 16);
            a1 += wB1 * __uint_as_float(pv1 & 0xFFFF0000u);
            zA += wA1; zB += wB1;
            if (C > 128 && lane == 0){
                a2 += wL0 * finz(g_Te[s0]); zL += wL0;
                a2 += wL1 * finz(g_Te[s1]); zL += wL1;
            }
        }
        if (t < m){
            int s0 = __shfl(sA, t * H);
            float wA0 = __shfl(w, t * H + h0);
            float wB0 = __shfl(w, t * H + h1);
            float wL0 = __shfl(w, t * H + (H - 1));
            unsigned pv0 = ((const unsigned*)(g_Tb + (size_t)s0 * TSTRIDE))[lane];
            a0 += wA0 * __uint_as_float(pv0 << 16);
            a1 += wB0 * __uint_as_float(pv0 & 0xFFFF0000u);
            zA += wA0; zB += wB0;
            if (C > 128 && lane == 0){
                a2 += wL0 * finz(g_Te[s0]); zL += wL0;
            }
        }
    }
    float o0 = finz(a0 / (zA + 1e-16f)) + finz(bias[c0]);
    float o1 = finz(a1 / (zB + 1e-16f)) + finz(bias[c1]);
    if (LEAKY){ o0 = lrelu(o0); o1 = lrelu(o1); }
    g_H[(size_t)n * HSTRIDE + c0] = finz(o0);
    g_H[(size_t)n * HSTRIDE + c1] = finz(o1);
    if (C > 128 && lane == 0){
        float o2 = finz(a2 / (zL + 1e-16f)) + finz(bias[128]);
        if (LEAKY) o2 = lrelu(o2);
        g_H[(size_t)n * HSTRIDE + 128] = finz(o2);
    }
}

// ---------------- pooling (batch sorted by construction) --------------------
__global__ void k_poolA(const int* __restrict__ batch){
    int c = threadIdx.x;              // 128 channels
    int n0 = blockIdx.x * 128;
    int bprev = -1; float acc = 0.f;
    for (int j = 0; j < 128; j++){
        int n = n0 + j;
        if (n >= N_NODES) break;
        int b = clampi(batch[n], 0, N_GRAPHS - 1);
        if (b != bprev){
            if (bprev >= 0) atomicAdd(&g_gsum[bprev * 128 + c], acc);
            acc = 0.f; bprev = b;
        }
        acc += finz(g_H[(size_t)n * HSTRIDE + c]);
    }
    if (bprev >= 0) atomicAdd(&g_gsum[bprev * 128 + c], acc);
}

// output is float32 (established r13/r14)
__global__ void k_fin(float* __restrict__ out){
    int idx = blockIdx.x * blockDim.x + threadIdx.x;
    if (idx >= N_GRAPHS * 128) return;
    int b = idx >> 7, c = idx & 127;
    out[b * 256 + c] = finz(finz(g_gsum[idx]) / fmaxf(g_gcnt[b], 1.f));
}

// ---------------- location MLP (+ per-graph count in block 64) --------------
__global__ void k_loc(const float* __restrict__ loc, const float* __restrict__ Wl1,
                      const float* __restrict__ bl1, const float* __restrict__ Wl2,
                      const float* __restrict__ bl2, float* __restrict__ out,
                      const int* __restrict__ batch){
    int b = blockIdx.x, t = threadIdx.x;
    if (b == N_GRAPHS){   // block 64: per-graph node counts via binary search
        if (t < N_GRAPHS){
            int lo = 0, hi = N_NODES;
            while (lo < hi){ int mid = (lo + hi) >> 1; if (batch[mid] <  t) lo = mid + 1; else hi = mid; }
            int start = lo;
            lo = 0; hi = N_NODES;
            while (lo < hi){ int mid = (lo + hi) >> 1; if (batch[mid] <= t) lo = mid + 1; else hi = mid; }
            g_gcnt[t] = (float)(lo - start);
        }
        return;
    }
    __shared__ float hs[256];
    float w0 = finz(Wl1[t]);
    float w1 = finz(Wl1[256 + t]);
    float bb = finz(bl1[t]);
    float s = 0.f;
    #pragma unroll 5
    for (int l = 0; l < N_LOCS; l++){
        float x0 = finz(loc[((size_t)b * N_LOCS + l) * 2]);
        float x1 = finz(loc[((size_t)b * N_LOCS + l) * 2 + 1]);
        s += tanhf(x0 * w0 + x1 * w1 + bb);
    }
    hs[t] = s;
    __syncthreads();
    if (t < 128){
        float acc = 0.f;
        #pragma unroll 8
        for (int j = 0; j < 256; j++) acc += hs[j] * finz(Wl2[(size_t)j * 128 + t]);
        out[(size_t)b * 256 + 128 + t] = finz(acc * (1.f / (float)N_LOCS) + finz(bl2[t]));
    }
}

// ---------------- launch ----------------
extern "C" void kernel_launch(void* const* d_in, const int* in_sizes, int n_in,
                              void* d_out, int out_size, void* d_ws, size_t ws_size,
                              hipStream_t stream){
    static const int want[20] = {300000, 6400, 1600000, 50000,
                                 774, 129, 129, 129,
                                 16641, 129, 129, 129,
                                 16512, 128, 128, 128,
                                 512, 256, 32768, 128};
    const void* P[20];
    bool assigned[20];
    for (int s = 0; s < 20; s++){ P[s] = nullptr; assigned[s] = false; }
    bool ok = (n_in == 20);
    if (ok){
        for (int i = 0; i < 20; i++){
            int sz = in_sizes[i], hit = -1;
            for (int s = 0; s < 20; s++)
                if (!assigned[s] && want[s] == sz){ hit = s; break; }
            if (hit < 0){ ok = false; break; }
            P[hit] = d_in[i]; assigned[hit] = true;
        }
        for (int s = 0; s < 20 && ok; s++) if (!assigned[s]) ok = false;
    }
    if (!ok) for (int s = 0; s < 20 && s < n_in; s++) P[s] = d_in[s];

    const float* x    = (const float*)P[0];
    const float* loc  = (const float*)P[1];
    const int*   ei   = (const int*)  P[2];
    const int*   batch= (const int*)  P[3];
    const float* W0   = (const float*)P[4];
    const float* as0  = (const float*)P[5];
    const float* ad0  = (const float*)P[6];
    const float* b0   = (const float*)P[7];
    const float* W1   = (const float*)P[8];
    const float* as1  = (const float*)P[9];
    const float* ad1  = (const float*)P[10];
    const float* b1   = (const float*)P[11];
    const float* W2   = (const float*)P[12];
    const float* as2  = (const float*)P[13];
    const float* ad2  = (const float*)P[14];
    const float* b2   = (const float*)P[15];
    const float* Wl1  = (const float*)P[16];
    const float* bl1  = (const float*)P[17];
    const float* Wl2  = (const float*)P[18];
    const float* bl2  = (const float*)P[19];
    float* out = (float*)d_out;
    (void)d_ws; (void)ws_size; (void)out_size;

    const int EB = (E_TOT + 255) / 256;
    const int GEMM_B = (N_NODES + 31) / 32;
    const int GB = (N_NODES + 3) / 4;

    k_pre    <<<(PRE_TOT + 255) / 256, 256, 0, stream>>>(W0, W1, W2);
    k_deg    <<<EB, 256, 0, stream>>>(ei);
    k_scan1  <<<SCAN_B, 256, 0, stream>>>();
    k_scan2  <<<1, 64, 0, stream>>>();
    k_scan3  <<<SCAN_B, 256, 0, stream>>>();
    k_fillcsr<<<EB, 256, 0, stream>>>(ei);

    // layer 0
    k_gemmf<0, 129><<<GEMM_B, 256, 0, stream>>>(x);
    k_esed<3, 43, 129><<<(N_NODES * 3 + 255) / 256, 256, 0, stream>>>(as0, ad0, 0);
    k_fgat<3, 43, 129, true><<<GB, 256, 0, stream>>>(b0, 0);

    // layer 1
    k_gemmf<1, 129><<<GEMM_B, 256, 0, stream>>>(x);
    k_esed<3, 43, 129><<<(N_NODES * 3 + 255) / 256, 256, 0, stream>>>(as1, ad1, 3);
    k_fgat<3, 43, 129, true><<<GB, 256, 0, stream>>>(b1, 3);

    // layer 2
    k_gemmf<2, 128><<<GEMM_B, 256, 0, stream>>>(x);
    k_esed<1, 128, 128><<<(N_NODES + 255) / 256, 256, 0, stream>>>(as2, ad2, 6);
    k_fgat<1, 128, 128, false><<<GB, 256, 0, stream>>>(b2, 6);

    // pooling + output
    k_poolA<<<(N_NODES + 127) / 128, 128, 0, stream>>>(batch);
    k_loc  <<<N_GRAPHS + 1, 256, 0, stream>>>(loc, Wl1, bl1, Wl2, bl2, out, batch);
    k_fin  <<<(N_GRAPHS * 128 + 255) / 256, 256, 0, stream>>>(out);
}

// Round 27
// 591.578 us; speedup vs baseline: 1.3265x; 1.0303x over previous
//
#include <hip/hip_runtime.h>
#include <hip/hip_bf16.h>
#include <math.h>

#define N_NODES  50000
#define N_EDGES  800000
#define E_TOT    850000   /* edges + self loops */
#define N_GRAPHS 64
#define N_LOCS   50
#define SCAN_B   ((N_NODES + 255) / 256)   /* 196 scan blocks */
#define TSTRIDE  128                       /* bf16 T row stride: 256B, 4 lines */
#define HSTRIDE  132                       /* f32 H row stride: 528B, 16B-aligned */

typedef __hip_bfloat16 bf16;

// ---------------- static scratch ----------------
__device__ int      g_deg[N_NODES];
__device__ int      g_cursor[N_NODES];
__device__ int      g_rowptr[N_NODES + 1];
__device__ int      g_bsum[SCAN_B];
__device__ int      g_csrc[E_TOT];               // CSR: src node per slot
__device__ float    g_Wp0[6 * 132];              // padded f32 weights per layer
__device__ float    g_Wp1[132 * 132];            // K zero-padded to 132 rows
__device__ float    g_Wp2[132 * 132];
__device__ __align__(256) unsigned short g_Tb[(size_t)N_NODES * TSTRIDE]; // T cols 0..127 (bf16)
__device__ float    g_Te[N_NODES];               // T col 128 (f32)
__device__ __align__(16) float g_H[(size_t)N_NODES * HSTRIDE]; // layer output (f32, pad cols zero)
__device__ float    g_es[N_NODES * 3];
__device__ float    g_ed[N_NODES * 3];
__device__ unsigned g_gmk[9];                    // per-layer global es max keys
__device__ float    g_gsum[N_GRAPHS * 128];
__device__ float    g_gcnt[N_GRAPHS];

// ---------------- helpers (dtypes settled: floats f32, ints int32) ----------
__device__ __forceinline__ float lrelu(float x){ return x > 0.f ? x : 0.2f * x; }
__device__ __forceinline__ int   clampi(int v, int lo, int hi){ return v < lo ? lo : (v > hi ? hi : v); }
__device__ __forceinline__ float finz(float v){
    unsigned u = __float_as_uint(v);
    return ((u & 0x7F800000u) == 0x7F800000u) ? 0.f : v;   // NaN/inf -> 0
}
__device__ __forceinline__ unsigned short f2bu(float x){
    union { bf16 b; unsigned short u; } cv; cv.b = __float2bfloat16(x); return cv.u;
}
__device__ __forceinline__ float bu2f(unsigned short u){ return __uint_as_float(((unsigned)u) << 16); }
__device__ __forceinline__ unsigned fkey(float f){
    unsigned u = __float_as_uint(f);
    return (u & 0x80000000u) ? ~u : (u | 0x80000000u);
}
__device__ __forceinline__ float kinv(unsigned k){
    return __uint_as_float((k & 0x80000000u) ? (k ^ 0x80000000u) : ~k);
}
__device__ __forceinline__ float expc(float a){ return __expf(fminf(fmaxf(a, -80.f), 0.f)); }
__device__ __forceinline__ void edge_sd(const int* ei, int e, int& src, int& dst){
    if (e < N_EDGES){
        src = clampi(ei[e], 0, N_NODES - 1);
        dst = clampi(ei[N_EDGES + e], 0, N_NODES - 1);
    } else {
        src = dst = e - N_EDGES;
    }
}

// ---------------- fused preprocessing: zero + pad all weights ---------------
// [deg 50000][gsum 8192][gmk 9][Wp0 792][Wp1 17424][Wp2 17424]
#define PRE_TOT (N_NODES + N_GRAPHS*128 + 9 + 6*132 + 132*132 + 132*132)
__global__ void k_pre(const float* __restrict__ W0, const float* __restrict__ W1,
                      const float* __restrict__ W2){
    int i = blockIdx.x * blockDim.x + threadIdx.x;
    if (i < N_NODES){ g_deg[i] = 0; return; }
    i -= N_NODES;
    if (i < N_GRAPHS * 128){ g_gsum[i] = 0.f; return; }
    i -= N_GRAPHS * 128;
    if (i < 9){ g_gmk[i] = 0u; return; }
    i -= 9;
    if (i < 6 * 132){
        int k = i / 132, c = i - k * 132;
        g_Wp0[i] = (c < 129) ? finz(W0[k * 129 + c]) : 0.f;
        return;
    }
    i -= 6 * 132;
    if (i < 132 * 132){
        int k = i / 132, c = i - k * 132;
        g_Wp1[i] = (k < 129 && c < 129) ? finz(W1[k * 129 + c]) : 0.f;
        return;
    }
    i -= 132 * 132;
    if (i < 132 * 132){
        int k = i / 132, c = i - k * 132;
        g_Wp2[i] = (k < 129 && c < 128) ? finz(W2[k * 128 + c]) : 0.f;
    }
}

// ---------------- CSR build ----------------
__global__ void k_deg(const int* __restrict__ ei){
    int e = blockIdx.x * blockDim.x + threadIdx.x;
    if (e >= E_TOT) return;
    int src, dst; edge_sd(ei, e, src, dst);
    atomicAdd(&g_deg[dst], 1);
}

__global__ void k_scan1(){
    __shared__ int s[256];
    int i = blockIdx.x * 256 + threadIdx.x;
    int v = (i < N_NODES) ? g_deg[i] : 0;
    s[threadIdx.x] = v;
    __syncthreads();
    for (int off = 1; off < 256; off <<= 1){
        int add = (threadIdx.x >= off) ? s[threadIdx.x - off] : 0;
        __syncthreads();
        s[threadIdx.x] += add;
        __syncthreads();
    }
    if (threadIdx.x == 255) g_bsum[blockIdx.x] = s[255];
    if (i < N_NODES) g_rowptr[i] = s[threadIdx.x] - v;
}

__global__ void k_scan2(){
    int lane = threadIdx.x;
    int carry = 0;
    for (int base = 0; base < SCAN_B; base += 64){
        int i = base + lane;
        int v = (i < SCAN_B) ? g_bsum[i] : 0;
        int s = v;
        #pragma unroll
        for (int off = 1; off < 64; off <<= 1){
            int t = __shfl_up(s, off);
            if (lane >= off) s += t;
        }
        if (i < SCAN_B) g_bsum[i] = carry + s - v;
        carry += __shfl(s, 63);
    }
    if (lane == 0) g_rowptr[N_NODES] = carry;
}

__global__ void k_scan3(){
    int i = blockIdx.x * 256 + threadIdx.x;
    if (i < N_NODES){
        int r = g_rowptr[i] + g_bsum[blockIdx.x];
        g_rowptr[i] = r;
        g_cursor[i] = r;
    }
}

__global__ void k_fillcsr(const int* __restrict__ ei){
    int e = blockIdx.x * blockDim.x + threadIdx.x;
    if (e >= E_TOT) return;
    int src, dst; edge_sd(ei, e, src, dst);
    int pos = atomicAdd(&g_cursor[dst], 1);
    if (pos >= 0 && pos < E_TOT) g_csrc[pos] = src;
}

// ---------------- GEMM: R rows/thread, float4 A and W, bf16 out -------------
// LAYER selects A/Wp in device code (device globals can't be host kernel args).
// Layers 1,2: A = g_H (stride 132, 16B-aligned), k padded to 132 with zero W
// rows (extra terms == 0, real-term accumulation order unchanged). R=8 gives
// 32 FMAs per W float4 load and 32 independent chains to cover L2 latency.
template<int LAYER, int CO, int R>
__global__ __launch_bounds__(256)
void k_gemmf(const float* __restrict__ X){
    const float* Wp = (LAYER == 0) ? g_Wp0 : (LAYER == 1 ? g_Wp1 : g_Wp2);
    int tid = threadIdx.x;
    int rg = tid >> 5;
    int g  = tid & 31;
    int n0 = blockIdx.x * (8 * R) + rg * R;
    const float4* wp = (const float4*)Wp;     // [rows][33] float4s
    float4 acc[R];
    float accE[R];
    #pragma unroll
    for (int r = 0; r < R; r++){ acc[r] = make_float4(0.f,0.f,0.f,0.f); accE[r] = 0.f; }

    if (LAYER == 0){
        const float* ar[R];
        #pragma unroll
        for (int r = 0; r < R; r++){
            int n = n0 + r;
            ar[r] = X + (size_t)(n < N_NODES ? n : N_NODES - 1) * 6;
        }
        #pragma unroll
        for (int k = 0; k < 6; k++){
            float4 w = wp[k * 33 + g];
            float we = (g == 0) ? Wp[k * 132 + 128] : 0.f;
            #pragma unroll
            for (int r = 0; r < R; r++){
                float a = ar[r][k];
                acc[r].x += a * w.x; acc[r].y += a * w.y;
                acc[r].z += a * w.z; acc[r].w += a * w.w;
                if (g == 0) accE[r] += a * we;
            }
        }
    } else {
        const float4* ar[R];
        #pragma unroll
        for (int r = 0; r < R; r++){
            int n = n0 + r;
            ar[r] = (const float4*)(g_H + (size_t)(n < N_NODES ? n : N_NODES - 1) * HSTRIDE);
        }
        for (int kk = 0; kk < 33; kk++){
            float4 a4[R];
            #pragma unroll
            for (int r = 0; r < R; r++) a4[r] = ar[r][kk];
            #pragma unroll
            for (int j = 0; j < 4; j++){
                int k = kk * 4 + j;
                float4 w = wp[k * 33 + g];
                float we = (CO > 128 && g == 0) ? Wp[k * 132 + 128] : 0.f;
                #pragma unroll
                for (int r = 0; r < R; r++){
                    float a = (j == 0) ? a4[r].x : (j == 1) ? a4[r].y : (j == 2) ? a4[r].z : a4[r].w;
                    acc[r].x += a * w.x; acc[r].y += a * w.y;
                    acc[r].z += a * w.z; acc[r].w += a * w.w;
                    if (CO > 128 && g == 0) accE[r] += a * we;
                }
            }
        }
    }

    #pragma unroll
    for (int r = 0; r < R; r++){
        int n = n0 + r;
        if (n >= N_NODES) break;
        unsigned* tw = (unsigned*)(g_Tb + (size_t)n * TSTRIDE);
        tw[g * 2]     = ((unsigned)f2bu(finz(acc[r].x)) ) | ((unsigned)f2bu(finz(acc[r].y)) << 16);
        tw[g * 2 + 1] = ((unsigned)f2bu(finz(acc[r].z)) ) | ((unsigned)f2bu(finz(acc[r].w)) << 16);
        if (CO > 128 && g == 0) g_Te[n] = finz(accE[r]);
    }
}

// ---------------- attention coefficients + fused global-max epilogue --------
template<int H, int O, int C>
__global__ void k_esed(const float* __restrict__ as, const float* __restrict__ ad,
                       int base){
    __shared__ unsigned sm[3];
    int tid = threadIdx.x;
    if (tid < H) sm[tid] = 0u;
    __syncthreads();
    int idx = blockIdx.x * blockDim.x + tid;
    if (idx < N_NODES * H){
        int n = idx / H, h = idx - n * H;
        float a = 0.f, b = 0.f;
        #pragma unroll 4
        for (int o = 0; o < O; o++){
            int col = h * O + o;
            float v = (col < 128) ? bu2f(g_Tb[(size_t)n * TSTRIDE + col]) : finz(g_Te[n]);
            a += v * finz(as[h * O + o]);
            b += v * finz(ad[h * O + o]);
        }
        a = finz(a); b = finz(b);
        g_es[idx] = a; g_ed[idx] = b;
        atomicMax(&sm[h], fkey(a));
    }
    __syncthreads();
    if (tid < H) atomicMax(&g_gmk[base + tid], sm[tid]);
}

// ------- FUSED softmax+gather, single edge sweep, 2-edge unrolled -----------
template<int H, int O, int C, bool LEAKY>
__global__ __launch_bounds__(256)
void k_fgat(const float* __restrict__ bias, int base){
    const int CH = 64 / H;               // 21 for H=3, 64 for H=1
    int wv = threadIdx.x >> 6, lane = threadIdx.x & 63;
    int n = blockIdx.x * 4 + wv;
    if (n >= N_NODES) return;
    int r0 = clampi(g_rowptr[n], 0, E_TOT);
    int r1 = clampi(g_rowptr[n + 1], r0, E_TOT);

    float edv[H], mx[H];
    #pragma unroll
    for (int h = 0; h < H; h++){
        edv[h] = finz(g_ed[n * H + h]);
        mx[h] = lrelu(finz(kinv(g_gmk[base + h])) + edv[h]);   // upper bound
    }

    const int c0 = 2 * lane, c1 = 2 * lane + 1;
    const int h0 = c0 / O, h1 = c1 / O;
    const int jmine = lane / H;
    const int hmine = lane - jmine * H;
    const float edm = edv[hmine], mxm = mx[hmine];
    float a0 = 0.f, a1 = 0.f, a2 = 0.f;
    float zA = 0.f, zB = 0.f, zL = 0.f;
    for (int bse = r0; bse < r1; bse += CH){
        int m = r1 - bse; if (m > CH) m = CH;
        // phase A: cooperative weight computation (1 exp per lane)
        float w = 0.f; int sA = 0;
        if (jmine < m){
            sA = clampi(g_csrc[bse + jmine], 0, N_NODES - 1);
            w = expc(lrelu(finz(g_es[sA * H + hmine]) + edm) - mxm);
        }
        // phase B: gather, 2 edges per iteration (2 row loads in flight)
        int t = 0;
        for (; t + 1 < m; t += 2){
            int s0 = __shfl(sA, t * H);
            int s1 = __shfl(sA, (t + 1) * H);
            float wA0 = __shfl(w, t * H + h0);
            float wB0 = __shfl(w, t * H + h1);
            float wA1 = __shfl(w, (t + 1) * H + h0);
            float wB1 = __shfl(w, (t + 1) * H + h1);
            float wL0 = __shfl(w, t * H + (H - 1));
            float wL1 = __shfl(w, (t + 1) * H + (H - 1));
            unsigned pv0 = ((const unsigned*)(g_Tb + (size_t)s0 * TSTRIDE))[lane];
            unsigned pv1 = ((const unsigned*)(g_Tb + (size_t)s1 * TSTRIDE))[lane];
            a0 += wA0 * __uint_as_float(pv0 << 16);
            a1 += wB0 * __uint_as_float(pv0 & 0xFFFF0000u);
            zA += wA0; zB += wB0;
            a0 += wA1 * __uint_as_float(pv1 << 16);
            a1 += wB1 * __uint_as_float(pv1 & 0xFFFF0000u);
            zA += wA1; zB += wB1;
            if (C > 128 && lane == 0){
                a2 += wL0 * finz(g_Te[s0]); zL += wL0;
                a2 += wL1 * finz(g_Te[s1]); zL += wL1;
            }
        }
        if (t < m){
            int s0 = __shfl(sA, t * H);
            float wA0 = __shfl(w, t * H + h0);
            float wB0 = __shfl(w, t * H + h1);
            float wL0 = __shfl(w, t * H + (H - 1));
            unsigned pv0 = ((const unsigned*)(g_Tb + (size_t)s0 * TSTRIDE))[lane];
            a0 += wA0 * __uint_as_float(pv0 << 16);
            a1 += wB0 * __uint_as_float(pv0 & 0xFFFF0000u);
            zA += wA0; zB += wB0;
            if (C > 128 && lane == 0){
                a2 += wL0 * finz(g_Te[s0]); zL += wL0;
            }
        }
    }
    float o0 = finz(a0 / (zA + 1e-16f)) + finz(bias[c0]);
    float o1 = finz(a1 / (zB + 1e-16f)) + finz(bias[c1]);
    if (LEAKY){ o0 = lrelu(o0); o1 = lrelu(o1); }
    g_H[(size_t)n * HSTRIDE + c0] = finz(o0);
    g_H[(size_t)n * HSTRIDE + c1] = finz(o1);
    if (C > 128 && lane == 0){
        float o2 = finz(a2 / (zL + 1e-16f)) + finz(bias[128]);
        if (LEAKY) o2 = lrelu(o2);
        g_H[(size_t)n * HSTRIDE + 128] = finz(o2);
    }
}

// ---------------- pooling (batch sorted by construction) --------------------
__global__ void k_poolA(const int* __restrict__ batch){
    int c = threadIdx.x;              // 128 channels
    int n0 = blockIdx.x * 128;
    int bprev = -1; float acc = 0.f;
    for (int j = 0; j < 128; j++){
        int n = n0 + j;
        if (n >= N_NODES) break;
        int b = clampi(batch[n], 0, N_GRAPHS - 1);
        if (b != bprev){
            if (bprev >= 0) atomicAdd(&g_gsum[bprev * 128 + c], acc);
            acc = 0.f; bprev = b;
        }
        acc += finz(g_H[(size_t)n * HSTRIDE + c]);
    }
    if (bprev >= 0) atomicAdd(&g_gsum[bprev * 128 + c], acc);
}

// output is float32 (established r13/r14)
__global__ void k_fin(float* __restrict__ out){
    int idx = blockIdx.x * blockDim.x + threadIdx.x;
    if (idx >= N_GRAPHS * 128) return;
    int b = idx >> 7, c = idx & 127;
    out[b * 256 + c] = finz(finz(g_gsum[idx]) / fmaxf(g_gcnt[b], 1.f));
}

// ---------------- location MLP (+ per-graph count in block 64) --------------
__global__ void k_loc(const float* __restrict__ loc, const float* __restrict__ Wl1,
                      const float* __restrict__ bl1, const float* __restrict__ Wl2,
                      const float* __restrict__ bl2, float* __restrict__ out,
                      const int* __restrict__ batch){
    int b = blockIdx.x, t = threadIdx.x;
    if (b == N_GRAPHS){   // block 64: per-graph node counts via binary search
        if (t < N_GRAPHS){
            int lo = 0, hi = N_NODES;
            while (lo < hi){ int mid = (lo + hi) >> 1; if (batch[mid] <  t) lo = mid + 1; else hi = mid; }
            int start = lo;
            lo = 0; hi = N_NODES;
            while (lo < hi){ int mid = (lo + hi) >> 1; if (batch[mid] <= t) lo = mid + 1; else hi = mid; }
            g_gcnt[t] = (float)(lo - start);
        }
        return;
    }
    __shared__ float hs[256];
    float w0 = finz(Wl1[t]);
    float w1 = finz(Wl1[256 + t]);
    float bb = finz(bl1[t]);
    float s = 0.f;
    #pragma unroll 5
    for (int l = 0; l < N_LOCS; l++){
        float x0 = finz(loc[((size_t)b * N_LOCS + l) * 2]);
        float x1 = finz(loc[((size_t)b * N_LOCS + l) * 2 + 1]);
        s += tanhf(x0 * w0 + x1 * w1 + bb);
    }
    hs[t] = s;
    __syncthreads();
    if (t < 128){
        float acc = 0.f;
        #pragma unroll 8
        for (int j = 0; j < 256; j++) acc += hs[j] * finz(Wl2[(size_t)j * 128 + t]);
        out[(size_t)b * 256 + 128 + t] = finz(acc * (1.f / (float)N_LOCS) + finz(bl2[t]));
    }
}

// ---------------- launch ----------------
extern "C" void kernel_launch(void* const* d_in, const int* in_sizes, int n_in,
                              void* d_out, int out_size, void* d_ws, size_t ws_size,
                              hipStream_t stream){
    static const int want[20] = {300000, 6400, 1600000, 50000,
                                 774, 129, 129, 129,
                                 16641, 129, 129, 129,
                                 16512, 128, 128, 128,
                                 512, 256, 32768, 128};
    const void* P[20];
    bool assigned[20];
    for (int s = 0; s < 20; s++){ P[s] = nullptr; assigned[s] = false; }
    bool ok = (n_in == 20);
    if (ok){
        for (int i = 0; i < 20; i++){
            int sz = in_sizes[i], hit = -1;
            for (int s = 0; s < 20; s++)
                if (!assigned[s] && want[s] == sz){ hit = s; break; }
            if (hit < 0){ ok = false; break; }
            P[hit] = d_in[i]; assigned[hit] = true;
        }
        for (int s = 0; s < 20 && ok; s++) if (!assigned[s]) ok = false;
    }
    if (!ok) for (int s = 0; s < 20 && s < n_in; s++) P[s] = d_in[s];

    const float* x    = (const float*)P[0];
    const float* loc  = (const float*)P[1];
    const int*   ei   = (const int*)  P[2];
    const int*   batch= (const int*)  P[3];
    const float* W0   = (const float*)P[4];
    const float* as0  = (const float*)P[5];
    const float* ad0  = (const float*)P[6];
    const float* b0   = (const float*)P[7];
    const float* W1   = (const float*)P[8];
    const float* as1  = (const float*)P[9];
    const float* ad1  = (const float*)P[10];
    const float* b1   = (const float*)P[11];
    const float* W2   = (const float*)P[12];
    const float* as2  = (const float*)P[13];
    const float* ad2  = (const float*)P[14];
    const float* b2   = (const float*)P[15];
    const float* Wl1  = (const float*)P[16];
    const float* bl1  = (const float*)P[17];
    const float* Wl2  = (const float*)P[18];
    const float* bl2  = (const float*)P[19];
    float* out = (float*)d_out;
    (void)d_ws; (void)ws_size; (void)out_size;

    const int EB = (E_TOT + 255) / 256;
    const int GEMM_B4 = (N_NODES + 31) / 32;   // R=4: 32 rows/block
    const int GEMM_B8 = (N_NODES + 63) / 64;   // R=8: 64 rows/block
    const int GB = (N_NODES + 3) / 4;

    k_pre    <<<(PRE_TOT + 255) / 256, 256, 0, stream>>>(W0, W1, W2);
    k_deg    <<<EB, 256, 0, stream>>>(ei);
    k_scan1  <<<SCAN_B, 256, 0, stream>>>();
    k_scan2  <<<1, 64, 0, stream>>>();
    k_scan3  <<<SCAN_B, 256, 0, stream>>>();
    k_fillcsr<<<EB, 256, 0, stream>>>(ei);

    // layer 0
    k_gemmf<0, 129, 4><<<GEMM_B4, 256, 0, stream>>>(x);
    k_esed<3, 43, 129><<<(N_NODES * 3 + 255) / 256, 256, 0, stream>>>(as0, ad0, 0);
    k_fgat<3, 43, 129, true><<<GB, 256, 0, stream>>>(b0, 0);

    // layer 1
    k_gemmf<1, 129, 8><<<GEMM_B8, 256, 0, stream>>>(x);
    k_esed<3, 43, 129><<<(N_NODES * 3 + 255) / 256, 256, 0, stream>>>(as1, ad1, 3);
    k_fgat<3, 43, 129, true><<<GB, 256, 0, stream>>>(b1, 3);

    // layer 2
    k_gemmf<2, 128, 8><<<GEMM_B8, 256, 0, stream>>>(x);
    k_esed<1, 128, 128><<<(N_NODES + 255) / 256, 256, 0, stream>>>(as2, ad2, 6);
    k_fgat<1, 128, 128, false><<<GB, 256, 0, stream>>>(b2, 6);

    // pooling + output
    k_poolA<<<(N_NODES + 127) / 128, 128, 0, stream>>>(batch);
    k_loc  <<<N_GRAPHS + 1, 256, 0, stream>>>(loc, Wl1, bl1, Wl2, bl2, out, batch);
    k_fin  <<<(N_GRAPHS * 128 + 255) / 256, 256, 0, stream>>>(out);
}